// Round 3
// baseline (191.852 us; speedup 1.0000x reference)
//
#include <hip/hip_runtime.h>
#include <math.h>

#define HW   (224 * 224)
#define TXW 32
#define TYH 8
#define HX 34
#define HY 10
#define PS 72                   // ushorts per halo pixel (64 ch + pad) -> 144 B, 16B-aligned
#define NSTAGE (HX * HY * 16)   // 5440 float4 stage items

typedef __attribute__((ext_vector_type(8))) short bf16x8;
typedef __attribute__((ext_vector_type(4))) float f32x4;

__device__ __forceinline__ unsigned bf16rne(float f) {
  unsigned u = __float_as_uint(f);
  u += 0x7fffu + ((u >> 16) & 1u);
  return u >> 16;
}

// ---------------------------------------------------------------------------
// kpack: 64 threads.
//  - wwv[j] = sum_d w3[d][j]^2 (fp32, shuffle reduce)
//  - B fragments for mfma_f32_16x16x32_bf16, split precision:
//    pass 0: bf16(w), pass 1: bf16(w - fp32(bf16(w))).
//    Layout wb[pass][kk][lane][i] (16B per (pass,kk,lane)): lane: col=l&15,
//    kgrp=l>>4; k = kk*32 + kgrp*8 + i; tap-major k = s*64+c, source d = c*9+s.
// ---------------------------------------------------------------------------
__global__ void kpack(const float* __restrict__ w1, const float* __restrict__ w2,
                      const float* __restrict__ w3, const float* __restrict__ w4,
                      const float* __restrict__ w5, unsigned short* __restrict__ wb,
                      float* __restrict__ wwv)
{
  const int lane = threadIdx.x;
  float pw0=0.f, pw1=0.f, pw2=0.f, pw3=0.f;
  for (int it = 0; it < 9; ++it) {
    const int d = lane + it*64;
    const float v0=w3[d*4+0], v1=w3[d*4+1], v2=w3[d*4+2], v3=w3[d*4+3];
    pw0=fmaf(v0,v0,pw0); pw1=fmaf(v1,v1,pw1); pw2=fmaf(v2,v2,pw2); pw3=fmaf(v3,v3,pw3);
  }
  for (int off = 32; off > 0; off >>= 1) {
    pw0 += __shfl_down(pw0,off); pw1 += __shfl_down(pw1,off);
    pw2 += __shfl_down(pw2,off); pw3 += __shfl_down(pw3,off);
  }
  if (lane == 0) { wwv[0]=pw0; wwv[1]=pw1; wwv[2]=pw2; wwv[3]=pw3; }

  for (int item = lane; item < 2304; item += 64) {   // 2 pass * 18 kk * 64 lane
    const int pass = item / 1152;
    const int rem  = item - pass*1152;
    const int kk   = rem >> 6;
    const int l    = rem & 63;
    const int col  = l & 15, kg = l >> 4;
    unsigned short hs[8];
#pragma unroll
    for (int i = 0; i < 8; ++i) {
      const int k = kk*32 + kg*8 + i;
      const int s = k >> 6, c = k & 63;
      const int d = c*9 + s;
      float v = (col==0) ? w1[d] : (col==1) ? w2[d] :
                (col<6)  ? w3[d*4 + (col-2)] :
                (col<11) ? w4[d*5 + (col-6)] : w5[d*5 + (col-11)];
      unsigned hb = bf16rne(v);
      if (pass) {
        const float r = v - __uint_as_float(hb << 16);
        hb = bf16rne(r);
      }
      hs[i] = (unsigned short)hb;
    }
    uint4 pk;
    pk.x = hs[0] | ((unsigned)hs[1] << 16);
    pk.y = hs[2] | ((unsigned)hs[3] << 16);
    pk.z = hs[4] | ((unsigned)hs[5] << 16);
    pk.w = hs[6] | ((unsigned)hs[7] << 16);
    ((uint4*)wb)[item] = pk;
  }
}

// ---------------------------------------------------------------------------
// kmain: block = 256 thr (4 waves), tile 32x8 px. Stage halo 34x10 as bf16 in
// LDS + fp32 per-pixel sum-of-squares; each wave computes 4 MFMA tiles
// (16 px x 16 out), K=576 in 18 chunks x 2 weight passes (hi/lo).
// ---------------------------------------------------------------------------
__global__ __launch_bounds__(256) void kmain(
    const float* __restrict__ x, const unsigned short* __restrict__ wb,
    const float* __restrict__ wwv, const float* __restrict__ gpt,
    const float* __restrict__ c4p, const float* __restrict__ c5p,
    float* __restrict__ out)
{
  __shared__ __align__(16) unsigned short xl[HX*HY*PS];  // 48960 B
  __shared__ float s2l[HX*HY];                           // 1360 B
  __shared__ float xxl[TXW*TYH];                         // 1024 B

  const int tid = threadIdx.x;
  const int bid = blockIdx.x;
  const int b   = bid / 196;
  const int t   = bid - b*196;
  const int tyi = t / 7;
  const int txi = t - tyi*7;
  const int y0  = tyi * TYH;
  const int x0  = txi * TXW;
  const float* __restrict__ xb = x + (size_t)b * HW * 64;

  // ---- Stage: fp32 -> bf16 LDS, plus per-pixel sum(x^2) in fp32 ----
  for (int idx = tid; idx < NSTAGE; idx += 256) {
    const int f4 = idx & 15;
    const int px = idx >> 4;
    const int hy = px / HX;
    const int hx = px - hy*HX;
    const int gy = y0 + hy - 1;
    const int gx = x0 + hx - 1;
    float4 v = make_float4(0.f, 0.f, 0.f, 0.f);
    if ((unsigned)gy < 224u && (unsigned)gx < 224u)
      v = *(const float4*)(xb + ((size_t)gy*224 + gx)*64 + f4*4);
    float p2 = fmaf(v.x, v.x, fmaf(v.y, v.y, fmaf(v.z, v.z, v.w*v.w)));
    p2 += __shfl_xor(p2, 1);
    p2 += __shfl_xor(p2, 2);
    p2 += __shfl_xor(p2, 4);
    p2 += __shfl_xor(p2, 8);
    uint2 pk;
    pk.x = bf16rne(v.x) | (bf16rne(v.y) << 16);
    pk.y = bf16rne(v.z) | (bf16rne(v.w) << 16);
    *(uint2*)&xl[px*PS + f4*4] = pk;
    if (f4 == 0) s2l[px] = p2;
  }
  __syncthreads();

  // ---- xx = 3x3 box sum of s2 ----
  {
    const int ox = tid & 31, oy = tid >> 5;
    float s = 0.f;
#pragma unroll
    for (int dy = 0; dy < 3; ++dy)
#pragma unroll
      for (int dx = 0; dx < 3; ++dx)
        s += s2l[(oy+dy)*HX + (ox+dx)];
    xxl[tid] = s;
  }
  __syncthreads();

  // ---- MFMA main loop ----
  const int lane   = tid & 63;
  const int wv     = tid >> 6;
  const int colsel = lane & 15;     // B col / A row / D col
  const int kg     = lane >> 4;     // k-group

  f32x4 acc[4];
#pragma unroll
  for (int j = 0; j < 4; ++j) acc[j] = (f32x4){0.f, 0.f, 0.f, 0.f};

  const bf16x8* __restrict__ wbv = (const bf16x8*)wb;

#pragma unroll
  for (int pass = 0; pass < 2; ++pass) {
    bf16x8 bfr[18];
#pragma unroll
    for (int kk = 0; kk < 18; ++kk)
      bfr[kk] = wbv[(pass*18 + kk)*64 + lane];
#pragma unroll
    for (int j = 0; j < 4; ++j) {
      const int tt = wv*4 + j;
      const int ty = tt >> 1;
      const int xh = (tt & 1) * 16;
      const unsigned short* __restrict__ ap =
          &xl[(ty*HX + xh + colsel)*PS + kg*8];
#pragma unroll
      for (int kk = 0; kk < 18; ++kk) {
        const int s  = kk >> 1;
        const int ky = s / 3, kx = s - ky*3;
        const bf16x8 a = *(const bf16x8*)(ap + (ky*HX + kx)*PS + (kk & 1)*32);
        acc[j] = __builtin_amdgcn_mfma_f32_16x16x32_bf16(a, bfr[kk], acc[j], 0, 0, 0);
      }
    }
  }

  // ---- Epilogue: per-column nonlinearity, D layout col=lane&15, row=kg*4+r ----
  const float g = gpt[0], cc4 = c4p[0], cc5 = c5p[0];
  const float wwsel = (colsel >= 2 && colsel < 6) ? wwv[colsel - 2] : 0.f;

#pragma unroll
  for (int j = 0; j < 4; ++j) {
    const int tt = wv*4 + j;
    const int ty = tt >> 1;
    const int xh = (tt & 1) * 16;
    float rv[4], xr[4];
#pragma unroll
    for (int r = 0; r < 4; ++r) {
      rv[r] = acc[j][r];
      xr[r] = xxl[ty*TXW + xh + kg*4 + r];
    }
    if (colsel == 1) {
#pragma unroll
      for (int r = 0; r < 4; ++r) rv[r] = tanhf(rv[r]);
    } else if (colsel >= 2 && colsel < 6) {
#pragma unroll
      for (int r = 0; r < 4; ++r) rv[r] = expf(-g * (xr[r] - 2.f*rv[r] + wwsel));
    } else if (colsel >= 6 && colsel < 11) {
#pragma unroll
      for (int r = 0; r < 4; ++r) { const float u = rv[r] + cc4; rv[r] = u*u*u; }
    } else if (colsel >= 11) {
#pragma unroll
      for (int r = 0; r < 4; ++r) { const float u = rv[r] + cc5; const float q = u*u; rv[r] = q*q*u; }
    }
    const int gy = y0 + ty;
#pragma unroll
    for (int r = 0; r < 4; ++r) {
      const int gx = x0 + xh + kg*4 + r;
      out[(((size_t)b*224 + gy)*224 + gx)*16 + colsel] = rv[r];
    }
  }
}

extern "C" void kernel_launch(void* const* d_in, const int* in_sizes, int n_in,
                              void* d_out, int out_size, void* d_ws, size_t ws_size,
                              hipStream_t stream) {
  const float* x  = (const float*)d_in[0];
  const float* w1 = (const float*)d_in[1];
  const float* w2 = (const float*)d_in[2];
  const float* w3 = (const float*)d_in[3];
  const float* w4 = (const float*)d_in[4];
  const float* w5 = (const float*)d_in[5];
  const float* g  = (const float*)d_in[6];
  const float* c4 = (const float*)d_in[7];
  const float* c5 = (const float*)d_in[8];
  float* out = (float*)d_out;

  unsigned short* wb = (unsigned short*)d_ws;          // 2*18*64*8 bf16 = 36864 B
  float* wwv = (float*)((char*)d_ws + 36864);          // 4 floats

  kpack<<<1, 64, 0, stream>>>(w1, w2, w3, w4, w5, wb, wwv);
  kmain<<<1568, 256, 0, stream>>>(x, wb, wwv, g, c4, c5, out);
}

// Round 4
// 62.980 us; speedup vs baseline: 3.0463x; 3.0463x over previous
//
#include <hip/hip_runtime.h>
#include <math.h>

#define HW   (224 * 224)
#define TXW 32
#define TYH 8
#define HX 34
#define HY 10
#define NPXH (HX * HY)          // 340 halo pixels
#define NUNIT (NPXH * 8)        // 2720 16B-units to stage

typedef __attribute__((ext_vector_type(8))) short bf16x8;
typedef __attribute__((ext_vector_type(4))) float f32x4;

__device__ __forceinline__ unsigned bf16rne(float f) {
  unsigned u = __float_as_uint(f);
  u += 0x7fffu + ((u >> 16) & 1u);
  return u >> 16;
}

// ---------------------------------------------------------------------------
// kpack: grid 10 x 256. Blocks 0..8: one B-fragment item per thread (2304
// items: pass*1152 + kk*64 + lane). Block 9: wwv[j] = sum_d w3[d][j]^2.
// Split precision: pass0 = bf16(w), pass1 = bf16(w - fp32(bf16(w))).
// ---------------------------------------------------------------------------
__global__ __launch_bounds__(256) void kpack(
    const float* __restrict__ w1, const float* __restrict__ w2,
    const float* __restrict__ w3, const float* __restrict__ w4,
    const float* __restrict__ w5, unsigned short* __restrict__ wb,
    float* __restrict__ wwv)
{
  const int tid = threadIdx.x;
  const int bid = blockIdx.x;
  if (bid == 9) {
    if (tid < 64) {
      const int lane = tid;
      float pw0=0.f, pw1=0.f, pw2=0.f, pw3=0.f;
      for (int it = 0; it < 9; ++it) {
        const int d = lane + it*64;
        const float v0=w3[d*4+0], v1=w3[d*4+1], v2=w3[d*4+2], v3=w3[d*4+3];
        pw0=fmaf(v0,v0,pw0); pw1=fmaf(v1,v1,pw1);
        pw2=fmaf(v2,v2,pw2); pw3=fmaf(v3,v3,pw3);
      }
      for (int off = 32; off > 0; off >>= 1) {
        pw0 += __shfl_down(pw0,off); pw1 += __shfl_down(pw1,off);
        pw2 += __shfl_down(pw2,off); pw3 += __shfl_down(pw3,off);
      }
      if (lane == 0) { wwv[0]=pw0; wwv[1]=pw1; wwv[2]=pw2; wwv[3]=pw3; }
    }
    return;
  }
  const int item = bid*256 + tid;        // 0..2303
  const int pass = item / 1152;
  const int rem  = item - pass*1152;
  const int kk   = rem >> 6;
  const int l    = rem & 63;
  const int col  = l & 15, kg = l >> 4;
  unsigned short hs[8];
#pragma unroll
  for (int i = 0; i < 8; ++i) {
    const int k = kk*32 + kg*8 + i;
    const int s = k >> 6, c = k & 63;
    const int d = c*9 + s;
    float v = (col==0) ? w1[d] : (col==1) ? w2[d] :
              (col<6)  ? w3[d*4 + (col-2)] :
              (col<11) ? w4[d*5 + (col-6)] : w5[d*5 + (col-11)];
    unsigned hb = bf16rne(v);
    if (pass) {
      const float r = v - __uint_as_float(hb << 16);
      hb = bf16rne(r);
    }
    hs[i] = (unsigned short)hb;
  }
  uint4 pk;
  pk.x = hs[0] | ((unsigned)hs[1] << 16);
  pk.y = hs[2] | ((unsigned)hs[3] << 16);
  pk.z = hs[4] | ((unsigned)hs[5] << 16);
  pk.w = hs[6] | ((unsigned)hs[7] << 16);
  ((uint4*)wb)[item] = pk;
}

// ---------------------------------------------------------------------------
// kmain: 256 thr (4 waves), tile 32x8 px. Halo 34x10 staged as bf16 in LDS
// with XOR swizzle: 16B unit u of pixel px lives at slot (u ^ (px&7)).
// Each wave: 4 MFMA tiles (16px x 16out), K=576 in 18 chunks; A-fragment
// read once per chunk, used by both weight passes (hi+lo bf16).
// B streamed from global (L1/L2-hot), prefetched 1 chunk ahead.
// ---------------------------------------------------------------------------
__global__ __launch_bounds__(256, 3) void kmain(
    const float* __restrict__ x, const unsigned short* __restrict__ wb,
    const float* __restrict__ wwv, const float* __restrict__ gpt,
    const float* __restrict__ c4p, const float* __restrict__ c5p,
    float* __restrict__ out)
{
  __shared__ __align__(16) uint4 xl16[NPXH * 8];   // 43520 B
  __shared__ float s2l[NPXH];                      // 1360 B
  __shared__ float xxl[TXW * TYH];                 // 1024 B

  const int tid = threadIdx.x;
  const int bid = blockIdx.x;
  const int b   = bid / 196;
  const int t   = bid - b*196;
  const int tyi = t / 7;
  const int txi = t - tyi*7;
  const int y0  = tyi * TYH;
  const int x0  = txi * TXW;
  const float* __restrict__ xb = x + (size_t)b * HW * 64;

  // ---- Stage halo -> bf16 LDS (swizzled) + per-pixel sum(x^2) ----
  for (int item = tid; item < NUNIT; item += 256) {
    const int px = item >> 3;
    const int u  = item & 7;
    const int hy = px / HX;
    const int hx = px - hy*HX;
    const int gy = y0 + hy - 1;
    const int gx = x0 + hx - 1;
    float4 va = make_float4(0.f,0.f,0.f,0.f);
    float4 vb = make_float4(0.f,0.f,0.f,0.f);
    if ((unsigned)gy < 224u && (unsigned)gx < 224u) {
      const float* src = xb + ((size_t)gy*224 + gx)*64 + u*8;
      va = *(const float4*)src;
      vb = *(const float4*)(src + 4);
    }
    float p2 = fmaf(va.x,va.x, fmaf(va.y,va.y, fmaf(va.z,va.z, va.w*va.w)));
    p2 = fmaf(vb.x,vb.x, fmaf(vb.y,vb.y, fmaf(vb.z,vb.z, fmaf(vb.w,vb.w, p2))));
    p2 += __shfl_xor(p2, 1);
    p2 += __shfl_xor(p2, 2);
    p2 += __shfl_xor(p2, 4);
    uint4 pk;
    pk.x = bf16rne(va.x) | (bf16rne(va.y) << 16);
    pk.y = bf16rne(va.z) | (bf16rne(va.w) << 16);
    pk.z = bf16rne(vb.x) | (bf16rne(vb.y) << 16);
    pk.w = bf16rne(vb.z) | (bf16rne(vb.w) << 16);
    xl16[px*8 + (u ^ (px & 7))] = pk;
    if (u == 0) s2l[px] = p2;
  }
  __syncthreads();

  // ---- xx = 3x3 box sum of per-pixel sum(x^2) ----
  {
    const int ox = tid & 31, oy = tid >> 5;
    float s = 0.f;
#pragma unroll
    for (int dy = 0; dy < 3; ++dy)
#pragma unroll
      for (int dx = 0; dx < 3; ++dx)
        s += s2l[(oy+dy)*HX + (ox+dx)];
    xxl[tid] = s;
  }
  __syncthreads();

  // ---- MFMA main loop ----
  const int lane   = tid & 63;
  const int wv     = tid >> 6;
  const int colsel = lane & 15;
  const int kg     = lane >> 4;

  f32x4 acc[4];
#pragma unroll
  for (int j = 0; j < 4; ++j) acc[j] = (f32x4){0.f,0.f,0.f,0.f};

  int px0[4];
#pragma unroll
  for (int j = 0; j < 4; ++j) {
    const int tt = wv*4 + j;
    px0[j] = (tt >> 1)*HX + (tt & 1)*16 + colsel;
  }

  const bf16x8* __restrict__ wbv = (const bf16x8*)wb;
  bf16x8 b0 = wbv[lane];            // kk=0, pass 0
  bf16x8 b1 = wbv[18*64 + lane];    // kk=0, pass 1

#pragma unroll
  for (int kk = 0; kk < 18; ++kk) {
    bf16x8 nb0, nb1;
    if (kk < 17) {
      nb0 = wbv[(kk+1)*64 + lane];
      nb1 = wbv[(19+kk)*64 + lane];
    }
    const int s  = kk >> 1;
    const int ky = s / 3, kx = s - ky*3;
    const int off = ky*HX + kx;
    const int u   = (kk & 1)*4 + kg;
    bf16x8 a[4];
#pragma unroll
    for (int j = 0; j < 4; ++j) {
      const int px = px0[j] + off;
      a[j] = *(const bf16x8*)&xl16[px*8 + (u ^ (px & 7))];
    }
#pragma unroll
    for (int j = 0; j < 4; ++j)
      acc[j] = __builtin_amdgcn_mfma_f32_16x16x32_bf16(a[j], b0, acc[j], 0, 0, 0);
#pragma unroll
    for (int j = 0; j < 4; ++j)
      acc[j] = __builtin_amdgcn_mfma_f32_16x16x32_bf16(a[j], b1, acc[j], 0, 0, 0);
    b0 = nb0; b1 = nb1;
  }

  // ---- Epilogue: D layout col=lane&15, row=kg*4+r ----
  const float g = gpt[0], cc4 = c4p[0], cc5 = c5p[0];
  const float wwsel = (colsel >= 2 && colsel < 6) ? wwv[colsel - 2] : 0.f;

#pragma unroll
  for (int j = 0; j < 4; ++j) {
    const int tt = wv*4 + j;
    const int ty = tt >> 1;
    const int xh = (tt & 1)*16;
    float rv[4], xr[4];
#pragma unroll
    for (int r = 0; r < 4; ++r) {
      rv[r] = acc[j][r];
      xr[r] = xxl[ty*TXW + xh + kg*4 + r];
    }
    if (colsel == 1) {
#pragma unroll
      for (int r = 0; r < 4; ++r) rv[r] = tanhf(rv[r]);
    } else if (colsel >= 2 && colsel < 6) {
#pragma unroll
      for (int r = 0; r < 4; ++r) rv[r] = expf(-g * (xr[r] - 2.f*rv[r] + wwsel));
    } else if (colsel >= 6 && colsel < 11) {
#pragma unroll
      for (int r = 0; r < 4; ++r) { const float uq = rv[r] + cc4; rv[r] = uq*uq*uq; }
    } else if (colsel >= 11) {
#pragma unroll
      for (int r = 0; r < 4; ++r) { const float uq = rv[r] + cc5; const float q = uq*uq; rv[r] = q*q*uq; }
    }
    const int gy = y0 + ty;
#pragma unroll
    for (int r = 0; r < 4; ++r) {
      const int gx = x0 + xh + kg*4 + r;
      out[(((size_t)b*224 + gy)*224 + gx)*16 + colsel] = rv[r];
    }
  }
}

extern "C" void kernel_launch(void* const* d_in, const int* in_sizes, int n_in,
                              void* d_out, int out_size, void* d_ws, size_t ws_size,
                              hipStream_t stream) {
  const float* x  = (const float*)d_in[0];
  const float* w1 = (const float*)d_in[1];
  const float* w2 = (const float*)d_in[2];
  const float* w3 = (const float*)d_in[3];
  const float* w4 = (const float*)d_in[4];
  const float* w5 = (const float*)d_in[5];
  const float* g  = (const float*)d_in[6];
  const float* c4 = (const float*)d_in[7];
  const float* c5 = (const float*)d_in[8];
  float* out = (float*)d_out;

  unsigned short* wb = (unsigned short*)d_ws;   // 2*18*64*8 bf16 = 36864 B
  float* wwv = (float*)((char*)d_ws + 36864);   // 4 floats

  kpack<<<10, 256, 0, stream>>>(w1, w2, w3, w4, w5, wb, wwv);
  kmain<<<1568, 256, 0, stream>>>(x, wb, wwv, g, c4, c5, out);
}

// Round 5
// 55.272 us; speedup vs baseline: 3.4711x; 1.1394x over previous
//
#include <hip/hip_runtime.h>
#include <math.h>

#define HW   (224 * 224)
#define TXW 32
#define TYH 4
#define HX 34
#define HY 6
#define NPXH (HX * HY)          // 204 halo pixels
#define NUNIT (NPXH * 8)        // 1632 16B-units to stage
#define BPI ((224 / TYH) * (224 / TXW))   // 392 blocks per image

typedef __attribute__((ext_vector_type(8))) short bf16x8;
typedef __attribute__((ext_vector_type(4))) float f32x4;

__device__ __forceinline__ unsigned bf16rne(float f) {
  unsigned u = __float_as_uint(f);
  u += 0x7fffu + ((u >> 16) & 1u);
  return u >> 16;
}

__device__ __forceinline__ unsigned cvt_pk_bf16(float lo, float hi) {
  unsigned r;
  asm("v_cvt_pk_bf16_f32 %0, %1, %2" : "=v"(r) : "v"(lo), "v"(hi));
  return r;
}

// ---------------------------------------------------------------------------
// kpack: grid 10 x 256. Blocks 0..8: one B-fragment item per thread (2304
// items: pass*1152 + kk*64 + lane). Block 9: wwv[j] = sum_d w3[d][j]^2.
// Split precision: pass0 = bf16(w), pass1 = bf16(w - fp32(bf16(w))).
// ---------------------------------------------------------------------------
__global__ __launch_bounds__(256) void kpack(
    const float* __restrict__ w1, const float* __restrict__ w2,
    const float* __restrict__ w3, const float* __restrict__ w4,
    const float* __restrict__ w5, unsigned short* __restrict__ wb,
    float* __restrict__ wwv)
{
  const int tid = threadIdx.x;
  const int bid = blockIdx.x;
  if (bid == 9) {
    if (tid < 64) {
      const int lane = tid;
      float pw0=0.f, pw1=0.f, pw2=0.f, pw3=0.f;
      for (int it = 0; it < 9; ++it) {
        const int d = lane + it*64;
        const float v0=w3[d*4+0], v1=w3[d*4+1], v2=w3[d*4+2], v3=w3[d*4+3];
        pw0=fmaf(v0,v0,pw0); pw1=fmaf(v1,v1,pw1);
        pw2=fmaf(v2,v2,pw2); pw3=fmaf(v3,v3,pw3);
      }
      for (int off = 32; off > 0; off >>= 1) {
        pw0 += __shfl_down(pw0,off); pw1 += __shfl_down(pw1,off);
        pw2 += __shfl_down(pw2,off); pw3 += __shfl_down(pw3,off);
      }
      if (lane == 0) { wwv[0]=pw0; wwv[1]=pw1; wwv[2]=pw2; wwv[3]=pw3; }
    }
    return;
  }
  const int item = bid*256 + tid;        // 0..2303
  const int pass = item / 1152;
  const int rem  = item - pass*1152;
  const int kk   = rem >> 6;
  const int l    = rem & 63;
  const int col  = l & 15, kg = l >> 4;
  unsigned short hs[8];
#pragma unroll
  for (int i = 0; i < 8; ++i) {
    const int k = kk*32 + kg*8 + i;
    const int s = k >> 6, c = k & 63;
    const int d = c*9 + s;
    float v = (col==0) ? w1[d] : (col==1) ? w2[d] :
              (col<6)  ? w3[d*4 + (col-2)] :
              (col<11) ? w4[d*5 + (col-6)] : w5[d*5 + (col-11)];
    unsigned hb = bf16rne(v);
    if (pass) {
      const float r = v - __uint_as_float(hb << 16);
      hb = bf16rne(r);
    }
    hs[i] = (unsigned short)hb;
  }
  uint4 pk;
  pk.x = hs[0] | ((unsigned)hs[1] << 16);
  pk.y = hs[2] | ((unsigned)hs[3] << 16);
  pk.z = hs[4] | ((unsigned)hs[5] << 16);
  pk.w = hs[6] | ((unsigned)hs[7] << 16);
  ((uint4*)wb)[item] = pk;
}

// ---------------------------------------------------------------------------
// kmain: 256 thr (4 waves), tile 32x4 px, halo 34x6 staged as bf16 in LDS
// with XOR swizzle (16B unit u of pixel px at slot u ^ (px&7)).
// Each wave: 2 MFMA tiles (16px x 16out), K=576 in 18 chunks; A-fragment
// read once per chunk, used by both weight passes (hi+lo bf16).
// B streamed from global (L1/L2-hot), prefetched 1 chunk ahead.
// 27.4 KB LDS -> 5 blocks/CU for stage/compute phase overlap across blocks.
// ---------------------------------------------------------------------------
__global__ __launch_bounds__(256, 5) void kmain(
    const float* __restrict__ x, const unsigned short* __restrict__ wb,
    const float* __restrict__ wwv, const float* __restrict__ gpt,
    const float* __restrict__ c4p, const float* __restrict__ c5p,
    float* __restrict__ out)
{
  __shared__ __align__(16) uint4 xl16[NPXH * 8];   // 26112 B
  __shared__ float s2l[NPXH];                      // 816 B
  __shared__ float xxl[TXW * TYH];                 // 512 B

  const int tid = threadIdx.x;
  const int bid = blockIdx.x;
  const int b   = bid / BPI;
  const int t   = bid - b*BPI;
  const int tyi = t / 7;
  const int txi = t - tyi*7;
  const int y0  = tyi * TYH;
  const int x0  = txi * TXW;
  const float* __restrict__ xb = x + (size_t)b * HW * 64;

  const int lane   = tid & 63;
  const int wv     = tid >> 6;
  const int colsel = lane & 15;
  const int kg     = lane >> 4;

  // Early B loads (kk=0, both passes) -- overlap with staging.
  const bf16x8* __restrict__ wbv = (const bf16x8*)wb;
  bf16x8 b0 = wbv[lane];
  bf16x8 b1 = wbv[18*64 + lane];

  // ---- Stage halo -> bf16 LDS (swizzled) + per-pixel sum(x^2) ----
  for (int item = tid; item < NUNIT; item += 256) {
    const int px = item >> 3;
    const int u  = item & 7;
    const int hy = px / HX;
    const int hx = px - hy*HX;
    const int gy = y0 + hy - 1;
    const int gx = x0 + hx - 1;
    float4 va = make_float4(0.f,0.f,0.f,0.f);
    float4 vb = make_float4(0.f,0.f,0.f,0.f);
    if ((unsigned)gy < 224u && (unsigned)gx < 224u) {
      const float* src = xb + ((size_t)gy*224 + gx)*64 + u*8;
      va = *(const float4*)src;
      vb = *(const float4*)(src + 4);
    }
    float p2 = fmaf(va.x,va.x, fmaf(va.y,va.y, fmaf(va.z,va.z, va.w*va.w)));
    p2 = fmaf(vb.x,vb.x, fmaf(vb.y,vb.y, fmaf(vb.z,vb.z, fmaf(vb.w,vb.w, p2))));
    p2 += __shfl_xor(p2, 1);
    p2 += __shfl_xor(p2, 2);
    p2 += __shfl_xor(p2, 4);
    uint4 pk;
    pk.x = cvt_pk_bf16(va.x, va.y);
    pk.y = cvt_pk_bf16(va.z, va.w);
    pk.z = cvt_pk_bf16(vb.x, vb.y);
    pk.w = cvt_pk_bf16(vb.z, vb.w);
    xl16[px*8 + (u ^ (px & 7))] = pk;
    if (u == 0) s2l[px] = p2;
  }
  __syncthreads();

  // ---- xx = 3x3 box sum of per-pixel sum(x^2) ----
  if (tid < TXW * TYH) {
    const int ox = tid & 31, oy = tid >> 5;
    float s = 0.f;
#pragma unroll
    for (int dy = 0; dy < 3; ++dy)
#pragma unroll
      for (int dx = 0; dx < 3; ++dx)
        s += s2l[(oy+dy)*HX + (ox+dx)];
    xxl[tid] = s;
  }
  __syncthreads();

  // ---- MFMA main loop: 2 tiles per wave ----
  f32x4 acc[2];
#pragma unroll
  for (int j = 0; j < 2; ++j) acc[j] = (f32x4){0.f,0.f,0.f,0.f};

  int px0[2];
#pragma unroll
  for (int j = 0; j < 2; ++j) {
    const int tt = wv*2 + j;
    px0[j] = (tt >> 1)*HX + (tt & 1)*16 + colsel;
  }

#pragma unroll
  for (int kk = 0; kk < 18; ++kk) {
    bf16x8 nb0, nb1;
    if (kk < 17) {
      nb0 = wbv[(kk+1)*64 + lane];
      nb1 = wbv[(19+kk)*64 + lane];
    }
    const int s  = kk >> 1;
    const int ky = s / 3, kx = s - ky*3;
    const int off = ky*HX + kx;
    const int u   = (kk & 1)*4 + kg;
    bf16x8 a[2];
#pragma unroll
    for (int j = 0; j < 2; ++j) {
      const int px = px0[j] + off;
      a[j] = *(const bf16x8*)&xl16[px*8 + (u ^ (px & 7))];
    }
#pragma unroll
    for (int j = 0; j < 2; ++j)
      acc[j] = __builtin_amdgcn_mfma_f32_16x16x32_bf16(a[j], b0, acc[j], 0, 0, 0);
#pragma unroll
    for (int j = 0; j < 2; ++j)
      acc[j] = __builtin_amdgcn_mfma_f32_16x16x32_bf16(a[j], b1, acc[j], 0, 0, 0);
    b0 = nb0; b1 = nb1;
  }

  // ---- Epilogue: D layout col=lane&15, row=kg*4+r ----
  const float g = gpt[0], cc4 = c4p[0], cc5 = c5p[0];
  const float wwsel = (colsel >= 2 && colsel < 6) ? wwv[colsel - 2] : 0.f;

#pragma unroll
  for (int j = 0; j < 2; ++j) {
    const int tt = wv*2 + j;
    const int ty = tt >> 1;
    const int xh = (tt & 1)*16;
    float rv[4], xr[4];
#pragma unroll
    for (int r = 0; r < 4; ++r) {
      rv[r] = acc[j][r];
      xr[r] = xxl[ty*TXW + xh + kg*4 + r];
    }
    if (colsel == 1) {
#pragma unroll
      for (int r = 0; r < 4; ++r) rv[r] = tanhf(rv[r]);
    } else if (colsel >= 2 && colsel < 6) {
#pragma unroll
      for (int r = 0; r < 4; ++r) rv[r] = expf(-g * (xr[r] - 2.f*rv[r] + wwsel));
    } else if (colsel >= 6 && colsel < 11) {
#pragma unroll
      for (int r = 0; r < 4; ++r) { const float uq = rv[r] + cc4; rv[r] = uq*uq*uq; }
    } else if (colsel >= 11) {
#pragma unroll
      for (int r = 0; r < 4; ++r) { const float uq = rv[r] + cc5; const float q = uq*uq; rv[r] = q*q*uq; }
    }
    const int gy = y0 + ty;
#pragma unroll
    for (int r = 0; r < 4; ++r) {
      const int gx = x0 + xh + kg*4 + r;
      out[(((size_t)b*224 + gy)*224 + gx)*16 + colsel] = rv[r];
    }
  }
}

extern "C" void kernel_launch(void* const* d_in, const int* in_sizes, int n_in,
                              void* d_out, int out_size, void* d_ws, size_t ws_size,
                              hipStream_t stream) {
  const float* x  = (const float*)d_in[0];
  const float* w1 = (const float*)d_in[1];
  const float* w2 = (const float*)d_in[2];
  const float* w3 = (const float*)d_in[3];
  const float* w4 = (const float*)d_in[4];
  const float* w5 = (const float*)d_in[5];
  const float* g  = (const float*)d_in[6];
  const float* c4 = (const float*)d_in[7];
  const float* c5 = (const float*)d_in[8];
  float* out = (float*)d_out;

  unsigned short* wb = (unsigned short*)d_ws;   // 2*18*64*8 bf16 = 36864 B
  float* wwv = (float*)((char*)d_ws + 36864);   // 4 floats

  kpack<<<10, 256, 0, stream>>>(w1, w2, w3, w4, w5, wb, wwv);
  kmain<<<8 * BPI, 256, 0, stream>>>(x, wb, wwv, g, c4, c5, out);
}